// Round 3
// baseline (214.689 us; speedup 1.0000x reference)
//
#include <hip/hip_runtime.h>
#include <math.h>

#define NN 4194304
#define NG 8192
#define TSTEPS 1000

// ws layout (floats): [0]=alpha, [1]=sigma, [4..4+8192] = start[] (ints, 8193),
// [8200 ..] = mean as float4[8192]  (byte offset 32800, 16B aligned)

// Parallel clipped-cumprod: step_j = clip(A[j+1]/A[j], 1e-3, 1) with
// A[0]=1, A[j+1]=(1-(j/T)^3)^2. P_t = prod_{j<=t} step_j (tree reduction).
__global__ __launch_bounds__(256) void k_alpha(const int* __restrict__ t_ptr,
                                               float* __restrict__ wsf) {
    int t = t_ptr[0];
    int tid = threadIdx.x;
    double partial = 1.0;
    #pragma unroll
    for (int k = 0; k < 4; ++k) {
        int j = tid * 4 + k;                 // covers 0..1023 >= TSTEPS
        if (j <= TSTEPS && j <= t) {
            double xj = (double)j / (double)TSTEPS;
            double num = 1.0 - xj * xj * xj; num *= num;      // A[j+1]
            double den = 1.0;                                  // A[j]
            if (j > 0) {
                double xp = (double)(j - 1) / (double)TSTEPS;
                den = 1.0 - xp * xp * xp; den *= den;
            }
            double step = num / den;
            step = fmin(fmax(step, 0.001), 1.0);
            partial *= step;
        }
    }
    #pragma unroll
    for (int off = 1; off < 64; off <<= 1)
        partial *= __shfl_xor(partial, off);
    __shared__ double wprod[4];
    int lane = tid & 63, wid = tid >> 6;
    if (lane == 0) wprod[wid] = partial;
    __syncthreads();
    if (tid == 0) {
        double P = wprod[0] * wprod[1] * wprod[2] * wprod[3];
        double at = (1.0 - 2.0e-4) * P + 1.0e-4;
        wsf[0] = (float)at;
        wsf[1] = (float)sqrt(1.0 - at * at);
    }
}

// start[s] = first index i with batch_index[i] >= s, for s in [0, NG]; start[NG]=N.
// Sorted input -> boundary detection; gap-fill covers empty segments.
__global__ void k_bounds(const int* __restrict__ bidx, int* __restrict__ start, int n) {
    int i = blockIdx.x * blockDim.x + threadIdx.x;
    if (i >= n) return;
    int b = bidx[i];
    if (i == 0) {
        for (int s = 0; s <= b; ++s) start[s] = 0;
    } else {
        int pb = bidx[i - 1];
        for (int s = pb + 1; s <= b; ++s) start[s] = i;
    }
    if (i == n - 1) {
        for (int s = b + 1; s <= NG; ++s) start[s] = n;
    }
}

// One block per segment; vectorized 3x float4 per 4-node group over the
// 16B-aligned interior, scalar loads for the <=3 edge nodes each side.
__global__ __launch_bounds__(256) void k_segmean(const float* __restrict__ noise,
                                                 const int* __restrict__ start,
                                                 float4* __restrict__ mean) {
    int s = blockIdx.x;
    int rs = start[s], re = start[s + 1];
    int cnt = re - rs;
    float sx = 0.f, sy = 0.f, sz = 0.f;
    int a0 = (rs + 3) >> 2;   // first full 4-node group
    int a1 = re >> 2;         // end group (exclusive)
    if (a1 > a0) {
        const float4* np = (const float4*)noise;
        for (int g = a0 + (int)threadIdx.x; g < a1; g += 256) {
            size_t p = (size_t)g * 3;
            float4 n0 = np[p], n1 = np[p + 1], n2 = np[p + 2];
            // lanes: n0=(x0,y0,z0,x1) n1=(y1,z1,x2,y2) n2=(z2,x3,y3,z3)
            sx += n0.x + n0.w + n1.z + n2.y;
            sy += n0.y + n1.x + n1.w + n2.z;
            sz += n0.z + n1.y + n2.x + n2.w;
        }
        int e0 = a0 * 4 - rs;   // leading scalar nodes (0..3)
        int e1 = re - a1 * 4;   // trailing scalar nodes (0..3)
        if ((int)threadIdx.x < e0) {
            int i = rs + (int)threadIdx.x;
            sx += noise[3 * i]; sy += noise[3 * i + 1]; sz += noise[3 * i + 2];
        }
        if ((int)threadIdx.x >= 4 && (int)threadIdx.x < 4 + e1) {
            int i = a1 * 4 + (int)threadIdx.x - 4;
            sx += noise[3 * i]; sy += noise[3 * i + 1]; sz += noise[3 * i + 2];
        }
    } else {
        for (int i = rs + (int)threadIdx.x; i < re; i += 256) {
            sx += noise[3 * i]; sy += noise[3 * i + 1]; sz += noise[3 * i + 2];
        }
    }
    #pragma unroll
    for (int off = 32; off > 0; off >>= 1) {
        sx += __shfl_down(sx, off);
        sy += __shfl_down(sy, off);
        sz += __shfl_down(sz, off);
    }
    __shared__ float red[3][4];
    int lane = threadIdx.x & 63, wid = threadIdx.x >> 6;
    if (lane == 0) { red[0][wid] = sx; red[1][wid] = sy; red[2][wid] = sz; }
    __syncthreads();
    if (threadIdx.x == 0) {
        float inv = 1.0f / (float)(cnt > 1 ? cnt : 1);
        float mx = (red[0][0] + red[0][1] + red[0][2] + red[0][3]) * inv;
        float my = (red[1][0] + red[1][1] + red[1][2] + red[1][3]) * inv;
        float mz = (red[2][0] + red[2][1] + red[2][2] + red[2][3]) * inv;
        mean[s] = make_float4(mx, my, mz, 0.f);
    }
}

// One thread per 4 nodes (12 floats = 3x float4 per array), fully coalesced.
__global__ __launch_bounds__(256) void k_main(const float* __restrict__ z,
                                              const float* __restrict__ noise,
                                              const int* __restrict__ bidx,
                                              const float* __restrict__ wsf,
                                              const float4* __restrict__ mean,
                                              float* __restrict__ out) {
    int g = blockIdx.x * blockDim.x + threadIdx.x;   // node group (4 nodes)
    float alpha = wsf[0], sigma = wsf[1];
    const float4* zp = (const float4*)z + (size_t)g * 3;
    const float4* np = (const float4*)noise + (size_t)g * 3;
    float4 z0 = zp[0], z1 = zp[1], z2 = zp[2];
    float4 n0 = np[0], n1 = np[1], n2 = np[2];
    int4 b = ((const int4*)bidx)[g];
    float4 m0 = mean[b.x], m1 = mean[b.y], m2 = mean[b.z], m3 = mean[b.w];

    // float lanes f0..f11 map to nodes {0,0,0,1},{1,1,2,2},{2,3,3,3} comps xyz cyclic
    float4 c0, c1, c2;
    c0.x = n0.x - m0.x; c0.y = n0.y - m0.y; c0.z = n0.z - m0.z; c0.w = n0.w - m1.x;
    c1.x = n1.x - m1.y; c1.y = n1.y - m1.z; c1.z = n1.z - m2.x; c1.w = n1.w - m2.y;
    c2.x = n2.x - m2.z; c2.y = n2.y - m3.x; c2.z = n2.z - m3.y; c2.w = n2.w - m3.z;

    float4 a0, a1, a2;
    a0.x = alpha * z0.x + sigma * c0.x; a0.y = alpha * z0.y + sigma * c0.y;
    a0.z = alpha * z0.z + sigma * c0.z; a0.w = alpha * z0.w + sigma * c0.w;
    a1.x = alpha * z1.x + sigma * c1.x; a1.y = alpha * z1.y + sigma * c1.y;
    a1.z = alpha * z1.z + sigma * c1.z; a1.w = alpha * z1.w + sigma * c1.w;
    a2.x = alpha * z2.x + sigma * c2.x; a2.y = alpha * z2.y + sigma * c2.y;
    a2.z = alpha * z2.z + sigma * c2.z; a2.w = alpha * z2.w + sigma * c2.w;

    float4* oz = (float4*)out + (size_t)g * 3;
    float4* oc = (float4*)(out + (size_t)NN * 3) + (size_t)g * 3;
    oz[0] = a0; oz[1] = a1; oz[2] = a2;
    oc[0] = c0; oc[1] = c1; oc[2] = c2;
}

extern "C" void kernel_launch(void* const* d_in, const int* in_sizes, int n_in,
                              void* d_out, int out_size, void* d_ws, size_t ws_size,
                              hipStream_t stream) {
    const float* z     = (const float*)d_in[0];
    const float* noise = (const float*)d_in[1];
    const int*   bidx  = (const int*)d_in[2];
    const int*   t     = (const int*)d_in[3];
    float* out = (float*)d_out;

    float*  wsf   = (float*)d_ws;
    int*    start = (int*)(wsf + 4);
    float4* mean  = (float4*)(wsf + 8200);

    k_alpha<<<1, 256, 0, stream>>>(t, wsf);
    k_bounds<<<NN / 256, 256, 0, stream>>>(bidx, start, NN);
    k_segmean<<<NG, 256, 0, stream>>>(noise, start, mean);
    k_main<<<NN / 4 / 256, 256, 0, stream>>>(z, noise, bidx, wsf, mean, out);
}

// Round 4
// 203.120 us; speedup vs baseline: 1.0570x; 1.0570x over previous
//
#include <hip/hip_runtime.h>
#include <math.h>

#define NN 4194304
#define NG 8192
#define TSTEPS 1000

// ws layout (floats): [0]=alpha, [1]=sigma, [4..4+8192] = start[] (ints, 8193)

// Parallel clipped-cumprod: step_j = clip(A[j+1]/A[j], 1e-3, 1) with
// A[0]=1, A[j+1]=(1-(j/T)^3)^2. P_t = prod_{j<=t} step_j (tree reduction).
__global__ __launch_bounds__(256) void k_alpha(const int* __restrict__ t_ptr,
                                               float* __restrict__ wsf) {
    int t = t_ptr[0];
    int tid = threadIdx.x;
    double partial = 1.0;
    #pragma unroll
    for (int k = 0; k < 4; ++k) {
        int j = tid * 4 + k;                 // covers 0..1023 >= TSTEPS
        if (j <= TSTEPS && j <= t) {
            double xj = (double)j / (double)TSTEPS;
            double num = 1.0 - xj * xj * xj; num *= num;      // A[j+1]
            double den = 1.0;                                  // A[j]
            if (j > 0) {
                double xp = (double)(j - 1) / (double)TSTEPS;
                den = 1.0 - xp * xp * xp; den *= den;
            }
            double step = num / den;
            step = fmin(fmax(step, 0.001), 1.0);
            partial *= step;
        }
    }
    #pragma unroll
    for (int off = 1; off < 64; off <<= 1)
        partial *= __shfl_xor(partial, off);
    __shared__ double wprod[4];
    int lane = tid & 63, wid = tid >> 6;
    if (lane == 0) wprod[wid] = partial;
    __syncthreads();
    if (tid == 0) {
        double P = wprod[0] * wprod[1] * wprod[2] * wprod[3];
        double at = (1.0 - 2.0e-4) * P + 1.0e-4;
        wsf[0] = (float)at;
        wsf[1] = (float)sqrt(1.0 - at * at);
    }
}

// start[s] = first index i with batch_index[i] >= s, for s in [0, NG]; start[NG]=N.
// Sorted input -> boundary detection; gap-fill covers empty segments.
__global__ void k_bounds(const int* __restrict__ bidx, int* __restrict__ start, int n) {
    int i = blockIdx.x * blockDim.x + threadIdx.x;
    if (i >= n) return;
    int b = bidx[i];
    if (i == 0) {
        for (int s = 0; s <= b; ++s) start[s] = 0;
    } else {
        int pb = bidx[i - 1];
        for (int s = pb + 1; s <= b; ++s) start[s] = i;
    }
    if (i == n - 1) {
        for (int s = b + 1; s <= NG; ++s) start[s] = n;
    }
}

// One block per segment: pass 1 reduces the segment's noise to a mean
// (segment ~6 KB -> stays L1-resident), pass 2 re-reads noise (L1 hit),
// reads z once, and writes both outputs. noise crosses HBM once, bidx never.
__global__ __launch_bounds__(256) void k_fused(const float* __restrict__ noise,
                                               const float* __restrict__ z,
                                               const int* __restrict__ start,
                                               const float* __restrict__ wsf,
                                               float* __restrict__ out) {
    int s = blockIdx.x;
    int rs = start[s], re = start[s + 1];
    int cnt = re - rs;
    int tid = threadIdx.x;

    float sx = 0.f, sy = 0.f, sz = 0.f;
    for (int i = rs + tid; i < re; i += 256) {
        sx += noise[3 * i + 0];
        sy += noise[3 * i + 1];
        sz += noise[3 * i + 2];
    }
    #pragma unroll
    for (int off = 32; off > 0; off >>= 1) {
        sx += __shfl_down(sx, off);
        sy += __shfl_down(sy, off);
        sz += __shfl_down(sz, off);
    }
    __shared__ float red[3][4];
    __shared__ float m[3];
    int lane = tid & 63, wid = tid >> 6;
    if (lane == 0) { red[0][wid] = sx; red[1][wid] = sy; red[2][wid] = sz; }
    __syncthreads();
    if (tid == 0) {
        float inv = 1.0f / (float)(cnt > 1 ? cnt : 1);
        m[0] = (red[0][0] + red[0][1] + red[0][2] + red[0][3]) * inv;
        m[1] = (red[1][0] + red[1][1] + red[1][2] + red[1][3]) * inv;
        m[2] = (red[2][0] + red[2][1] + red[2][2] + red[2][3]) * inv;
    }
    __syncthreads();
    float mx = m[0], my = m[1], mz = m[2];
    float alpha = wsf[0], sigma = wsf[1];

    float* __restrict__ oc = out + (size_t)NN * 3;
    for (int i = rs + tid; i < re; i += 256) {
        float cx = noise[3 * i + 0] - mx;   // L1/L2 hit
        float cy = noise[3 * i + 1] - my;
        float cz = noise[3 * i + 2] - mz;
        float zx = z[3 * i + 0];
        float zy = z[3 * i + 1];
        float zz = z[3 * i + 2];
        out[3 * i + 0] = alpha * zx + sigma * cx;
        out[3 * i + 1] = alpha * zy + sigma * cy;
        out[3 * i + 2] = alpha * zz + sigma * cz;
        oc[3 * i + 0] = cx;
        oc[3 * i + 1] = cy;
        oc[3 * i + 2] = cz;
    }
}

extern "C" void kernel_launch(void* const* d_in, const int* in_sizes, int n_in,
                              void* d_out, int out_size, void* d_ws, size_t ws_size,
                              hipStream_t stream) {
    const float* z     = (const float*)d_in[0];
    const float* noise = (const float*)d_in[1];
    const int*   bidx  = (const int*)d_in[2];
    const int*   t     = (const int*)d_in[3];
    float* out = (float*)d_out;

    float* wsf   = (float*)d_ws;
    int*   start = (int*)(wsf + 4);

    k_alpha<<<1, 256, 0, stream>>>(t, wsf);
    k_bounds<<<NN / 256, 256, 0, stream>>>(bidx, start, NN);
    k_fused<<<NG, 256, 0, stream>>>(noise, z, start, wsf, out);
}